// Round 1
// 1218.862 us; speedup vs baseline: 1.0113x; 1.0113x over previous
//
#include <hip/hip_runtime.h>

// IDWT_2D Haar: B=4, Ct=256 (C=64 groups x 4 subbands), H=W=256 -> out [4,256,512,512]
// y[b, g*4+j, 2h+a, 2w+c] = (sum_n x[b, n*64+g, h, w]) * filters[j,a,c]
//
// HBM-bound scatter: 256 MiB in + 1 GiB out => ~215 us kernel floor at 6.3 TB/s.
// (Measured harness dur_us also includes a ~690 us output re-poison fill.)
//
// This version: w-granularity 2 (was 4) so every float4 store instruction is
// wave-contiguous (byte off = 16*lane, 1024 B fully-covered per instruction)
// instead of 16B-at-stride-32 partial-line pairs. Non-temporal loads/stores:
// both streams are touch-once, skip L2/LLC allocation.

#define B   4
#define C   64      // wavelet groups
#define H   256
#define W   256
#define W2  (W / 2) // 2 w-positions per thread

typedef float f2 __attribute__((ext_vector_type(2)));
typedef float f4 __attribute__((ext_vector_type(4)));

__global__ __launch_bounds__(256) void idwt2d_haar_kernel(
    const float* __restrict__ x,     // [B, 4*C, H, W]
    const float* __restrict__ filt,  // [4, 2, 2]
    float* __restrict__ y)           // [B, 4*C, 2H, 2W]
{
    const int tid = blockIdx.x * 256 + threadIdx.x;
    // tid = ((b*C + g)*H + h)*W2 + w2
    const int w2 = tid & (W2 - 1);          // 7 bits
    const int h  = (tid >> 7) & (H - 1);    // 8 bits
    const int g  = (tid >> 15) & (C - 1);   // 6 bits
    const int b  = tid >> 21;               // 2 bits

    const int w = w2 << 1;  // starting w (2 consecutive input pixels)

    // input: x[b, n*C+g, h, w..w+1], n-stride = C*H*W
    const int nstride = C * H * W;
    const int in_base = (((b * (4 * C)) + g) * H + h) * W + w;

    const f2 x0 = __builtin_nontemporal_load((const f2*)(x + in_base));
    const f2 x1 = __builtin_nontemporal_load((const f2*)(x + in_base + nstride));
    const f2 x2 = __builtin_nontemporal_load((const f2*)(x + in_base + 2 * nstride));
    const f2 x3 = __builtin_nontemporal_load((const f2*)(x + in_base + 3 * nstride));

    // keep the same reduction tree as the verified kernel
    const float s0 = (x0.x + x1.x) + (x2.x + x3.x);
    const float s1 = (x0.y + x1.y) + (x2.y + x3.y);

    // output: y[b, g*4+j, 2h+a, 2w + 0..3]  -> one float4 per (j,a)
    const int out_ch0 = b * (4 * C) + (g << 2);  // channel of j=0
    const int row0 = h << 1;
    const int col0 = w << 1;                     // byte offset 16*w2: wave-contiguous

#pragma unroll
    for (int j = 0; j < 4; ++j) {
        const int ch_base = (out_ch0 + j) * (2 * H) * (2 * W);
#pragma unroll
        for (int a = 0; a < 2; ++a) {
            const float f0 = filt[j * 4 + a * 2 + 0];
            const float f1 = filt[j * 4 + a * 2 + 1];
            f4 o;
            o.x = s0 * f0;
            o.y = s0 * f1;
            o.z = s1 * f0;
            o.w = s1 * f1;
            __builtin_nontemporal_store(
                o, (f4*)(y + ch_base + (row0 + a) * (2 * W) + col0));
        }
    }
}

extern "C" void kernel_launch(void* const* d_in, const int* in_sizes, int n_in,
                              void* d_out, int out_size, void* d_ws, size_t ws_size,
                              hipStream_t stream) {
    const float* x    = (const float*)d_in[0];  // [4, 256, 256, 256] fp32
    const float* filt = (const float*)d_in[1];  // [4, 2, 2] fp32
    float* y = (float*)d_out;                   // [4, 256, 512, 512] fp32

    const int total_threads = B * C * H * W2;   // 8,388,608
    const int block = 256;
    const int grid = total_threads / block;     // 32768
    idwt2d_haar_kernel<<<grid, block, 0, stream>>>(x, filt, y);
}